// Round 8
// baseline (274.764 us; speedup 1.0000x reference)
//
#include <hip/hip_runtime.h>

// ---- problem geometry ----
#define D_MODEL 512
#define HD      1960
#define NPAD    2048          // HD padded to tile multiple
#define NVECS   720
#define MROWS   14400         // 4*3600
#define MPAD    14464         // 113*128
#define HP      66
#define WP      114
#define IMGPIX  7524          // HP*WP

typedef __bf16 bf16x8 __attribute__((ext_vector_type(8)));
typedef float  f32x4  __attribute__((ext_vector_type(4)));

__device__ __forceinline__ unsigned short f2bf(float f) {
    unsigned u = __builtin_bit_cast(unsigned, f);
    u += 0x7FFFu + ((u >> 16) & 1u);   // RNE
    return (unsigned short)(u >> 16);
}
__device__ __forceinline__ float bf2f(unsigned short s) {
    unsigned u = ((unsigned)s) << 16;
    return __builtin_bit_cast(float, u);
}

__device__ __forceinline__ void gload_lds16(const unsigned short* g, unsigned short* l) {
    __builtin_amdgcn_global_load_lds(
        (const __attribute__((address_space(1))) unsigned int*)g,
        (__attribute__((address_space(3))) unsigned int*)l,
        16, 0, 0);
}

// ---- convert x (fp32) -> bf16, zero-pad rows [14400,14464) ----
__global__ void cvt_x(const float* __restrict__ x, unsigned short* __restrict__ xb) {
    size_t i = ((size_t)blockIdx.x * 256 + threadIdx.x) * 4;
    const size_t valid = (size_t)MROWS * D_MODEL;
    if (i >= (size_t)MPAD * D_MODEL) return;
    ushort4 o;
    if (i < valid) {
        float4 v = *(const float4*)(x + i);
        o.x = f2bf(v.x); o.y = f2bf(v.y); o.z = f2bf(v.z); o.w = f2bf(v.w);
    } else {
        o.x = o.y = o.z = o.w = 0;
    }
    *(ushort4*)(xb + i) = o;
}

// ---- tiled transpose + fp32->bf16, zero-fill outside src ----
__global__ void transpose_cvt(const float* __restrict__ src, unsigned short* __restrict__ dst,
                              int srcR, int srcC, int dstR, int dstC) {
    __shared__ float tile[32][33];
    int c0 = blockIdx.x * 32;
    int r0 = blockIdx.y * 32;
    int tx = threadIdx.x, ty = threadIdx.y;   // (32,8)
    #pragma unroll
    for (int i = 0; i < 32; i += 8) {
        int sr = c0 + ty + i, sc = r0 + tx;
        tile[ty + i][tx] = (sr < srcR && sc < srcC) ? src[(size_t)sr * srcC + sc] : 0.f;
    }
    __syncthreads();
    #pragma unroll
    for (int i = 0; i < 32; i += 8) {
        int dr = r0 + ty + i, dc = c0 + tx;
        if (dr < dstR && dc < dstC)
            dst[(size_t)dr * dstC + dc] = f2bf(tile[tx][ty + i]);
    }
}

// ---- m97-style bf16 GEMM (R6-measured: 64us each): C = A(MxK) * BT(NxK)^T (+bias) ----
// MODE 0: out bf16 TRANSPOSED  hT[col*MPAD + row], skip cols >= validN (GEMM1)
// MODE 1: out fp32 row-major (ldc=512), skip rows >= validM           (GEMM2)
template<int MODE>
__global__ void gemm_bt(const unsigned short* __restrict__ A,
                        const unsigned short* __restrict__ BT,
                        const float* __restrict__ bias,
                        void* __restrict__ Cout,
                        int K, int ldc, int validN, int validM) {
    __shared__ unsigned short smem[128 * 128];   // 32 KB: As|Bs during K-loop, C-tile in epilogue
    unsigned short* As = smem;
    unsigned short* Bs = smem + 128 * 64;
    const int t    = threadIdx.x;
    const int wid  = t >> 6, lane = t & 63;
    const int wr   = wid >> 1, wc = wid & 1;
    const int lr   = lane & 15, lh = lane >> 4;
    const int m0   = blockIdx.y * 128, n0 = blockIdx.x * 128;

    f32x4 acc[4][4] = {};

    const unsigned short* Aptr = A  + (size_t)(m0 + (t >> 3)) * K + (t & 7) * 8;
    const unsigned short* Bptr = BT + (size_t)(n0 + (t >> 3)) * K + (t & 7) * 8;
    unsigned short* Asl = As + t * 8;
    unsigned short* Bsl = Bs + t * 8;

    for (int kt = 0; kt < K; kt += 64) {
        #pragma unroll
        for (int i = 0; i < 4; ++i) {
            gload_lds16(Aptr + (size_t)(i * 32) * K + kt, Asl + i * 2048);
            gload_lds16(Bptr + (size_t)(i * 32) * K + kt, Bsl + i * 2048);
        }
        __syncthreads();
        #pragma unroll
        for (int ks = 0; ks < 2; ++ks) {
            bf16x8 a[4], b[4];
            #pragma unroll
            for (int f = 0; f < 4; ++f) {
                a[f] = *(const bf16x8*)&As[(wr * 64 + f * 16 + lr) * 64 + ks * 32 + lh * 8];
                b[f] = *(const bf16x8*)&Bs[(wc * 64 + f * 16 + lr) * 64 + ks * 32 + lh * 8];
            }
            #pragma unroll
            for (int fm = 0; fm < 4; ++fm)
                #pragma unroll
                for (int fn = 0; fn < 4; ++fn)
                    acc[fm][fn] = __builtin_amdgcn_mfma_f32_16x16x32_bf16(
                        a[fm], b[fn], acc[fm][fn], 0, 0, 0);
        }
        __syncthreads();
    }

    // C/D layout: col=lane&15, row=(lane>>4)*4+j  [m89 verified]
    if (MODE == 0) {
        // stage C-tile (bias applied, bf16) into swizzled LDS, then write hT col-major coalesced
        #pragma unroll
        for (int fm = 0; fm < 4; ++fm) {
            #pragma unroll
            for (int fn = 0; fn < 4; ++fn) {
                int lcol = wc * 64 + fn * 16 + lr;
                float bv = bias[n0 + lcol];
                #pragma unroll
                for (int j = 0; j < 4; ++j) {
                    int lrow = wr * 64 + fm * 16 + lh * 4 + j;
                    smem[lcol * 128 + (lrow ^ ((lcol & 15) << 3))] =
                        f2bf(acc[fm][fn][j] + bv);
                }
            }
        }
        __syncthreads();
        unsigned short* hT = (unsigned short*)Cout;
        int col = t >> 1, half = t & 1;
        int gcol = n0 + col;
        if (gcol < validN) {
            #pragma unroll
            for (int r = 0; r < 16; ++r) {
                int row = half * 64 + r * 4;
                ushort4 v4 = *(const ushort4*)&smem[col * 128 + (row ^ ((col & 15) << 3))];
                *(ushort4*)&hT[(size_t)gcol * MPAD + m0 + row] = v4;
            }
        }
    } else {
        #pragma unroll
        for (int fm = 0; fm < 4; ++fm) {
            #pragma unroll
            for (int fn = 0; fn < 4; ++fn) {
                int gcol = n0 + wc * 64 + fn * 16 + lr;
                float bv = bias[gcol];
                #pragma unroll
                for (int j = 0; j < 4; ++j) {
                    int grow = m0 + wr * 64 + fm * 16 + lh * 4 + j;
                    if (grow < validM)
                        ((float*)Cout)[(size_t)grow * ldc + gcol] = acc[fm][fn][j] + bv;
                }
            }
        }
    }
}

// ---- fold + normalize + relu -> per-(b2,c) padded image (bf16) ----
// grid (HP, 200), block 128: y=blockIdx.x, blockIdx.y = b2*10+cg (4 channels/thread).
__global__ void fold_norm(const unsigned short* __restrict__ hT, unsigned short* __restrict__ img2) {
    int y  = blockIdx.x;
    int g  = blockIdx.y;
    int b2 = g / 10, cg = g % 10;
    int c0 = cg * 4;
    int x  = threadIdx.x;
    if (x >= WP) return;
    float val[4] = {0.f, 0.f, 0.f, 0.f};
    if (y >= 3 && y < 63 && x >= 3 && x < 111) {
        int kiA[3], biA[3], nki = 0;
        for (int ki = y % 3; ki < 7; ki += 3) {
            int bi = (y - ki) / 3;
            if (y - ki >= 0 && bi < 20) { kiA[nki] = ki; biA[nki] = bi; ++nki; }
        }
        int kjA[3], bjA[3], nkj = 0;
        for (int kj = x % 3; kj < 7; kj += 3) {
            int bj = (x - kj) / 3;
            if (x - kj >= 0 && bj < 36) { kjA[nkj] = kj; bjA[nkj] = bj; ++nkj; }
        }
        float s[4] = {0.f, 0.f, 0.f, 0.f};
        for (int i = 0; i < nki; ++i) {
            for (int j = 0; j < nkj; ++j) {
                int row = b2 * NVECS + biA[i] * 36 + bjA[j];
                int colb = kiA[i] * 7 + kjA[j];
                #pragma unroll
                for (int q = 0; q < 4; ++q)
                    s[q] += bf2f(hT[(size_t)((c0 + q) * 49 + colb) * MPAD + row]);
            }
        }
        float inv = 1.f / (float)(nki * nkj);
        #pragma unroll
        for (int q = 0; q < 4; ++q)
            val[q] = fmaxf(s[q] * inv, 0.f);
    }
    #pragma unroll
    for (int q = 0; q < 4; ++q)
        img2[(size_t)(b2 * 40 + c0 + q) * IMGPIX + y * WP + x] = f2bf(val[q]);
}

// ---- unfold: h2b[row][hd] = img2[b2,c, (bi*3+ki), (bj*3+kj)]; zero pads ----
// grid MPAD blocks x 256 threads; thread owns hd = 8t..8t+7 -> two ushort4 stores.
__global__ void unfold_k(const unsigned short* __restrict__ img2, unsigned short* __restrict__ h2b) {
    int row = blockIdx.x;             // 0..MPAD-1
    int t   = threadIdx.x;
    int hd0 = t * 8;
    unsigned short vals[8] = {0, 0, 0, 0, 0, 0, 0, 0};
    if (row < MROWS) {
        int b2 = row / NVECS, v = row % NVECS;
        int bi = v / 36, bj = v % 36;
        const unsigned short* base = img2 + (size_t)b2 * 40 * IMGPIX + (bi * 3) * WP + bj * 3;
        #pragma unroll
        for (int i = 0; i < 8; ++i) {
            int hd = hd0 + i;
            if (hd < HD) {
                int c = hd / 49, kk = hd % 49;
                int ki = kk / 7, kj = kk % 7;
                vals[i] = base[(size_t)c * IMGPIX + ki * WP + kj];
            }
        }
    }
    ushort4 lo = {vals[0], vals[1], vals[2], vals[3]};
    ushort4 hi = {vals[4], vals[5], vals[6], vals[7]};
    *(ushort4*)&h2b[(size_t)row * NPAD + hd0]     = lo;
    *(ushort4*)&h2b[(size_t)row * NPAD + hd0 + 4] = hi;
}

extern "C" void kernel_launch(void* const* d_in, const int* in_sizes, int n_in,
                              void* d_out, int out_size, void* d_ws, size_t ws_size,
                              hipStream_t stream) {
    const float* x  = (const float*)d_in[0];
    const float* W1 = (const float*)d_in[1];
    const float* b1 = (const float*)d_in[2];
    const float* W2 = (const float*)d_in[3];
    const float* b2 = (const float*)d_in[4];
    float* out = (float*)d_out;

    // workspace layout (bf16 elements), total ~149.5 MB
    unsigned short* xb   = (unsigned short*)d_ws;                 // MPAD*512
    unsigned short* W1T  = xb   + (size_t)MPAD * D_MODEL;         // 2048*512
    unsigned short* W2T  = W1T  + (size_t)NPAD * D_MODEL;         // 512*2048
    unsigned short* hT   = W2T  + (size_t)D_MODEL * NPAD;         // NPAD*MPAD (transposed)
    unsigned short* h2b  = hT   + (size_t)NPAD * MPAD;            // MPAD*NPAD
    unsigned short* img2 = h2b  + (size_t)MPAD * NPAD;            // 800*7524

    cvt_x<<<(MPAD * D_MODEL / 4 + 255) / 256, 256, 0, stream>>>(x, xb);

    dim3 tb(32, 8);
    transpose_cvt<<<dim3(512 / 32, NPAD / 32), tb, 0, stream>>>(W1, W1T, D_MODEL, HD, NPAD, D_MODEL);
    transpose_cvt<<<dim3(NPAD / 32, 512 / 32), tb, 0, stream>>>(W2, W2T, HD, D_MODEL, D_MODEL, NPAD);

    // GEMM1: hT = (xb @ W1T^T + b1)^T   (bf16, transposed out)
    gemm_bt<0><<<dim3(NPAD / 128, MPAD / 128), 256, 0, stream>>>(
        xb, W1T, b1, hT, D_MODEL, 0, HD, MPAD);

    fold_norm<<<dim3(HP, 200), 128, 0, stream>>>(hT, img2);
    unfold_k<<<MPAD, 256, 0, stream>>>(img2, h2b);

    // GEMM2: out = h2b @ W2T^T + b2  (fp32, rows<14400 only)
    gemm_bt<1><<<dim3(512 / 128, MPAD / 128), 256, 0, stream>>>(
        h2b, W2T, b2, out, NPAD, D_MODEL, D_MODEL, MROWS);
}

// Round 9
// 188.584 us; speedup vs baseline: 1.4570x; 1.4570x over previous
//
#include <hip/hip_runtime.h>

// ---- problem geometry ----
#define D_MODEL 512
#define HD      1960
#define NPAD    2048          // HD padded to tile multiple
#define NVECS   720
#define MROWS   14400         // 4*3600
#define MPAD    14464         // 113*128
#define HP      66
#define WP      114
#define IMGPIX  7524          // HP*WP

typedef __bf16 bf16x8 __attribute__((ext_vector_type(8)));
typedef float  f32x4  __attribute__((ext_vector_type(4)));

__device__ __forceinline__ unsigned short f2bf(float f) {
    unsigned u = __builtin_bit_cast(unsigned, f);
    u += 0x7FFFu + ((u >> 16) & 1u);   // RNE
    return (unsigned short)(u >> 16);
}
__device__ __forceinline__ float bf2f(unsigned short s) {
    unsigned u = ((unsigned)s) << 16;
    return __builtin_bit_cast(float, u);
}

__device__ __forceinline__ void gload_lds16(const unsigned short* g, unsigned short* l) {
    __builtin_amdgcn_global_load_lds(
        (const __attribute__((address_space(1))) unsigned int*)g,
        (__attribute__((address_space(3))) unsigned int*)l,
        16, 0, 0);
}

// ---- convert x (fp32) -> bf16, zero-pad rows [14400,14464) ----
__global__ void cvt_x(const float* __restrict__ x, unsigned short* __restrict__ xb) {
    size_t i = ((size_t)blockIdx.x * 256 + threadIdx.x) * 4;
    const size_t valid = (size_t)MROWS * D_MODEL;
    if (i >= (size_t)MPAD * D_MODEL) return;
    ushort4 o;
    if (i < valid) {
        float4 v = *(const float4*)(x + i);
        o.x = f2bf(v.x); o.y = f2bf(v.y); o.z = f2bf(v.z); o.w = f2bf(v.w);
    } else {
        o.x = o.y = o.z = o.w = 0;
    }
    *(ushort4*)(xb + i) = o;
}

// ---- tiled transpose + fp32->bf16, zero-fill outside src ----
__global__ void transpose_cvt(const float* __restrict__ src, unsigned short* __restrict__ dst,
                              int srcR, int srcC, int dstR, int dstC) {
    __shared__ float tile[32][33];
    int c0 = blockIdx.x * 32;
    int r0 = blockIdx.y * 32;
    int tx = threadIdx.x, ty = threadIdx.y;   // (32,8)
    #pragma unroll
    for (int i = 0; i < 32; i += 8) {
        int sr = c0 + ty + i, sc = r0 + tx;
        tile[ty + i][tx] = (sr < srcR && sc < srcC) ? src[(size_t)sr * srcC + sc] : 0.f;
    }
    __syncthreads();
    #pragma unroll
    for (int i = 0; i < 32; i += 8) {
        int dr = r0 + ty + i, dc = c0 + tx;
        if (dr < dstR && dc < dstC)
            dst[(size_t)dr * dstC + dc] = f2bf(tile[tx][ty + i]);
    }
}

// ---- m97-style bf16 GEMM (R6-measured: 64us each): C = A(MxK) * BT(NxK)^T (+bias) ----
// MODE 0: out bf16 TRANSPOSED  hT[col*MPAD + row], skip cols >= validN (GEMM1)
// MODE 1: out fp32 row-major (ldc=512), skip rows >= validM           (GEMM2)
template<int MODE>
__global__ void gemm_bt(const unsigned short* __restrict__ A,
                        const unsigned short* __restrict__ BT,
                        const float* __restrict__ bias,
                        void* __restrict__ Cout,
                        int K, int ldc, int validN, int validM) {
    __shared__ unsigned short smem[128 * 128];   // 32 KB: As|Bs during K-loop, C-tile in epilogue
    unsigned short* As = smem;
    unsigned short* Bs = smem + 128 * 64;
    const int t    = threadIdx.x;
    const int wid  = t >> 6, lane = t & 63;
    const int wr   = wid >> 1, wc = wid & 1;
    const int lr   = lane & 15, lh = lane >> 4;
    const int m0   = blockIdx.y * 128, n0 = blockIdx.x * 128;

    f32x4 acc[4][4] = {};

    const unsigned short* Aptr = A  + (size_t)(m0 + (t >> 3)) * K + (t & 7) * 8;
    const unsigned short* Bptr = BT + (size_t)(n0 + (t >> 3)) * K + (t & 7) * 8;
    unsigned short* Asl = As + t * 8;
    unsigned short* Bsl = Bs + t * 8;

    for (int kt = 0; kt < K; kt += 64) {
        #pragma unroll
        for (int i = 0; i < 4; ++i) {
            gload_lds16(Aptr + (size_t)(i * 32) * K + kt, Asl + i * 2048);
            gload_lds16(Bptr + (size_t)(i * 32) * K + kt, Bsl + i * 2048);
        }
        __syncthreads();
        #pragma unroll
        for (int ks = 0; ks < 2; ++ks) {
            bf16x8 a[4], b[4];
            #pragma unroll
            for (int f = 0; f < 4; ++f) {
                a[f] = *(const bf16x8*)&As[(wr * 64 + f * 16 + lr) * 64 + ks * 32 + lh * 8];
                b[f] = *(const bf16x8*)&Bs[(wc * 64 + f * 16 + lr) * 64 + ks * 32 + lh * 8];
            }
            #pragma unroll
            for (int fm = 0; fm < 4; ++fm)
                #pragma unroll
                for (int fn = 0; fn < 4; ++fn)
                    acc[fm][fn] = __builtin_amdgcn_mfma_f32_16x16x32_bf16(
                        a[fm], b[fn], acc[fm][fn], 0, 0, 0);
        }
        __syncthreads();
    }

    // C/D layout: col=lane&15, row=(lane>>4)*4+j  [m89 verified]
    if (MODE == 0) {
        // stage C-tile (bias applied, bf16) into swizzled LDS, then write hT col-major coalesced
        #pragma unroll
        for (int fm = 0; fm < 4; ++fm) {
            #pragma unroll
            for (int fn = 0; fn < 4; ++fn) {
                int lcol = wc * 64 + fn * 16 + lr;
                float bv = bias[n0 + lcol];
                #pragma unroll
                for (int j = 0; j < 4; ++j) {
                    int lrow = wr * 64 + fm * 16 + lh * 4 + j;
                    smem[lcol * 128 + (lrow ^ ((lcol & 15) << 3))] =
                        f2bf(acc[fm][fn][j] + bv);
                }
            }
        }
        __syncthreads();
        unsigned short* hT = (unsigned short*)Cout;
        int col = t >> 1, half = t & 1;
        int gcol = n0 + col;
        if (gcol < validN) {
            #pragma unroll
            for (int r = 0; r < 16; ++r) {
                int row = half * 64 + r * 4;
                ushort4 v4 = *(const ushort4*)&smem[col * 128 + (row ^ ((col & 15) << 3))];
                *(ushort4*)&hT[(size_t)gcol * MPAD + m0 + row] = v4;
            }
        }
    } else {
        #pragma unroll
        for (int fm = 0; fm < 4; ++fm) {
            #pragma unroll
            for (int fn = 0; fn < 4; ++fn) {
                int gcol = n0 + wc * 64 + fn * 16 + lr;
                float bv = bias[gcol];
                #pragma unroll
                for (int j = 0; j < 4; ++j) {
                    int grow = m0 + wr * 64 + fm * 16 + lh * 4 + j;
                    if (grow < validM)
                        ((float*)Cout)[(size_t)grow * ldc + gcol] = acc[fm][fn][j] + bv;
                }
            }
        }
    }
}

// ---- fold + normalize + relu -> per-(b2,c) padded image (bf16) ----
// grid (HP, 200), block 128: y=blockIdx.x, blockIdx.y = b2*10+cg (4 channels/thread).
__global__ void fold_norm(const unsigned short* __restrict__ hT, unsigned short* __restrict__ img2) {
    int y  = blockIdx.x;
    int g  = blockIdx.y;
    int b2 = g / 10, cg = g % 10;
    int c0 = cg * 4;
    int x  = threadIdx.x;
    if (x >= WP) return;
    float val[4] = {0.f, 0.f, 0.f, 0.f};
    if (y >= 3 && y < 63 && x >= 3 && x < 111) {
        int kiA[3], biA[3], nki = 0;
        for (int ki = y % 3; ki < 7; ki += 3) {
            int bi = (y - ki) / 3;
            if (y - ki >= 0 && bi < 20) { kiA[nki] = ki; biA[nki] = bi; ++nki; }
        }
        int kjA[3], bjA[3], nkj = 0;
        for (int kj = x % 3; kj < 7; kj += 3) {
            int bj = (x - kj) / 3;
            if (x - kj >= 0 && bj < 36) { kjA[nkj] = kj; bjA[nkj] = bj; ++nkj; }
        }
        float s[4] = {0.f, 0.f, 0.f, 0.f};
        for (int i = 0; i < nki; ++i) {
            for (int j = 0; j < nkj; ++j) {
                int row = b2 * NVECS + biA[i] * 36 + bjA[j];
                int colb = kiA[i] * 7 + kjA[j];
                #pragma unroll
                for (int q = 0; q < 4; ++q)
                    s[q] += bf2f(hT[(size_t)((c0 + q) * 49 + colb) * MPAD + row]);
            }
        }
        float inv = 1.f / (float)(nki * nkj);
        #pragma unroll
        for (int q = 0; q < 4; ++q)
            val[q] = fmaxf(s[q] * inv, 0.f);
    }
    #pragma unroll
    for (int q = 0; q < 4; ++q)
        img2[(size_t)(b2 * 40 + c0 + q) * IMGPIX + y * WP + x] = f2bf(val[q]);
}

// ---- unfold, LDS-staged: block (b2*20+bi, cg). Stage img2 slab, write h2b coalesced. ----
// cg=0 -> hd 0..979 (245 ushort4/row); cg=1 -> hd 980..2047 (267 ushort4/row, >=1960 zero).
// h2b pad rows [14400,14464) left unwritten: they only feed GEMM2 output rows >= validM (never stored).
__global__ void unfold_k(const unsigned short* __restrict__ img2, unsigned short* __restrict__ h2b) {
    __shared__ unsigned short lds[20 * 798];   // [cc][ki*114 + x], 15960 ushorts
    __shared__ unsigned short lut[980];        // hd_local -> cc*798 + ki*114 + kj
    const int gb = blockIdx.x;                 // b2*20 + bi
    const int cg = blockIdx.y;
    const int b2 = gb / 20, bi = gb % 20;
    const int t  = threadIdx.x;

    // stage: 7 image rows (y = bi*3 .. bi*3+6) x 114 cols x 20 channels, ushort2 loads
    const unsigned short* src = img2 + (size_t)(b2 * 40 + cg * 20) * IMGPIX + (bi * 3) * WP;
    for (int p = t; p < 7980; p += 256) {
        int cc = p / 399, rem2 = p - cc * 399;        // element pair within channel slab
        *(ushort2*)&lds[cc * 798 + rem2 * 2] =
            *(const ushort2*)&src[(size_t)cc * IMGPIX + rem2 * 2];
    }
    for (int L = t; L < 980; L += 256) {
        int cc = L / 49, kk = L - cc * 49;
        lut[L] = (unsigned short)(cc * 798 + (kk / 7) * 114 + (kk % 7));
    }
    __syncthreads();

    const int cpr   = (cg == 0) ? 245 : 267;          // ushort4 chunks per row
    const int total = 36 * cpr;
    const int rowbase = b2 * NVECS + bi * 36;
    const int hdbase  = cg * 980;
    for (int i = t; i < total; i += 256) {
        int r = i / cpr, q = i - r * cpr;
        int hl = q * 4;
        ushort4 v;
        unsigned short* vv = (unsigned short*)&v;
        #pragma unroll
        for (int e = 0; e < 4; ++e) {
            int h = hl + e;
            vv[e] = (h < 980) ? lds[lut[h] + r * 3] : (unsigned short)0;
        }
        *(ushort4*)&h2b[(size_t)(rowbase + r) * NPAD + hdbase + hl] = v;
    }
}

extern "C" void kernel_launch(void* const* d_in, const int* in_sizes, int n_in,
                              void* d_out, int out_size, void* d_ws, size_t ws_size,
                              hipStream_t stream) {
    const float* x  = (const float*)d_in[0];
    const float* W1 = (const float*)d_in[1];
    const float* b1 = (const float*)d_in[2];
    const float* W2 = (const float*)d_in[3];
    const float* b2 = (const float*)d_in[4];
    float* out = (float*)d_out;

    // workspace layout (bf16 elements), total ~149.5 MB
    unsigned short* xb   = (unsigned short*)d_ws;                 // MPAD*512
    unsigned short* W1T  = xb   + (size_t)MPAD * D_MODEL;         // 2048*512
    unsigned short* W2T  = W1T  + (size_t)NPAD * D_MODEL;         // 512*2048
    unsigned short* hT   = W2T  + (size_t)D_MODEL * NPAD;         // NPAD*MPAD (transposed)
    unsigned short* h2b  = hT   + (size_t)NPAD * MPAD;            // MPAD*NPAD
    unsigned short* img2 = h2b  + (size_t)MPAD * NPAD;            // 800*7524

    cvt_x<<<(MPAD * D_MODEL / 4 + 255) / 256, 256, 0, stream>>>(x, xb);

    dim3 tb(32, 8);
    transpose_cvt<<<dim3(512 / 32, NPAD / 32), tb, 0, stream>>>(W1, W1T, D_MODEL, HD, NPAD, D_MODEL);
    transpose_cvt<<<dim3(NPAD / 32, 512 / 32), tb, 0, stream>>>(W2, W2T, HD, D_MODEL, D_MODEL, NPAD);

    // GEMM1: hT = (xb @ W1T^T + b1)^T   (bf16, transposed out)
    gemm_bt<0><<<dim3(NPAD / 128, MPAD / 128), 256, 0, stream>>>(
        xb, W1T, b1, hT, D_MODEL, 0, HD, MPAD);

    fold_norm<<<dim3(HP, 200), 128, 0, stream>>>(hT, img2);
    unfold_k<<<dim3(400, 2), 256, 0, stream>>>(img2, h2b);

    // GEMM2: out = h2b @ W2T^T + b2  (fp32, rows<14400 only)
    gemm_bt<1><<<dim3(512 / 128, MPAD / 128), 256, 0, stream>>>(
        h2b, W2T, b2, out, NPAD, D_MODEL, D_MODEL, MROWS);
}